// Round 8
// baseline (250.971 us; speedup 1.0000x reference)
//
#include <hip/hip_runtime.h>

typedef __fp16 h2 __attribute__((ext_vector_type(2)));
typedef __fp16 h8 __attribute__((ext_vector_type(8)));
typedef float f4 __attribute__((ext_vector_type(4)));

namespace {
constexpr int JSTR = 72;          // halves per j-row (64 c + 8 pad) -> 144 B, breaks bank aliasing
constexpr int JROWS = 40;         // j = d+dz in [0,40): rows 40-47 never feed a valid (dz<9) output.
                                  // wv3's b128 reads at rows 40-47 read adjacent LDS (finite garbage),
                                  // contaminating only C rows m>=8, which the dz-mask never writes
                                  // (wv3: dz=16+m-l15<9 -> l15>=m+8 -> m<=7; MFMA C-row m depends only
                                  // on A-row m, held by lanes l15==m).
constexpr int COLH = JROWS * JSTR;  // 2880 halves = 5760 B per column buffer
}

// R8: T4 counted-drain barrier. R5/R7 fit: round latency = fixed ~1.2-1.4 us
// stall + work term; issue content per round is only ~15% of SIMD cycles.
// Theory: __syncthreads()'s implicit s_waitcnt vmcnt(0) drains the NT output
// stores (HBM-class ack) EVERY round. The barrier only protects LDS hazards;
// global stores have no reader. Replace with lgkmcnt(0)-only + raw s_barrier
// so stores (and any in-flight loads) pipeline across column rounds.
//
// Pipeline per column (ONE barrier):
//   1. issue next-column global loads -> regs        (T14 issue-early)
//   2. ds_read A-frags (once), MFMA x 4 pos
//   3. band-write acc -> obuf[ci&1]                  (obuf double-buffered)
//   4. readback column ci-1 from obuf[(ci-1)&1] -> global NT stores
//   5. cvt + ds_write staged regs -> colbuf[(ci+1)&1] (T14 write-late)
//   6. lgkmcnt(0) + s_barrier (NO vmcnt drain)
// Hazard audit (all LDS, all separated by lgkmcnt(0)+barrier):
//   colbuf[(ci+1)&1] write(5,ci)  vs read(2,ci+1)
//   colbuf[ci&1]     read(2,ci)   vs write(5,ci+1)
//   obuf[ci&1]       write(3,ci)  vs read(4,ci+1)
//   obuf[(ci-1)&1]   read(4,ci)   vs write(3,ci+1)   (data in regs at lgkmcnt(0);
//                                                     NT store holds its own regs)
__global__ __launch_bounds__(256, 7) void corr3d_mfma(
    const float* __restrict__ in1, const float* __restrict__ in2,
    float* __restrict__ out)
{
  __shared__ __align__(16) __fp16 colbuf[2][COLH];    // 11520 B
  __shared__ __align__(16) float obuf[2][4 * 288];    // [parity][pos*288+dz*32+d], 9216 B

  const int tid = threadIdx.x;
  // XCD-aware chunked swizzle: blocks sharing in2 are consecutive logical ids;
  // 2048 % 8 == 0 -> bijective, 256-block slab/XCD spans 8 h-rows (R2 evidence:
  // FETCH 303 MB -> 22 MB from this remap family).
  const int blk = ((blockIdx.x & 7) << 8) | (blockIdx.x >> 3);
  const int quarter = blk & 3;            // column-range quarter
  const int w0 = ((blk >> 2) & 7) << 2;   // four w positions: w0 .. w0+3
  const int h = (blk >> 5) & 31;
  const int b = blk >> 10;
  const int ciLo = quarter * 27;
  const int ciHi = ciLo + 27;             // 108 columns (9 hc x 12 wc) split x4

  const int lane = tid & 63;
  const int wv = tid >> 6;  // wave 0..3 = D-tiles (T0,s0),(T1,s0),(T1,s1),(T2,s1)
  const int jb = (wv == 0) ? 0 : (wv == 3) ? 32 : 16;  // A-tile j base
  const int db = (wv >= 2) ? 16 : 0;                   // d-strip base
  const int l15 = lane & 15;
  const int lhi = lane >> 4;

  const float* in1b = in1 + ((size_t)b << 21);
  const float* in2b = in2 + ((size_t)b << 21);

  // zero halo rows of both column buffers (j<4, j>=36): written once, never touched again
  for (int i = tid; i < 576; i += 256) {
    const int bu = i / 288;
    const int r = i - bu * 288;
    const int jrow = r / 36;
    const int cc = r - jrow * 36;
    const int j = (jrow < 4) ? jrow : jrow + 32;  // rows 0-3, 36-39
    h2 z = {(__fp16)0.f, (__fp16)0.f};
    *(h2*)&colbuf[bu][j * JSTR + cc * 2] = z;
  }

  // staging role: d = tid&31 (coalesced), c-quad = tid>>5
  const int sd = tid & 31;
  const int scq = tid >> 5;

  auto stage = [&](const float* src, bool valid, __fp16* dst) {
#pragma unroll
    for (int it = 0; it < 4; ++it) {
      const int cp = scq + (it << 3);  // c-pair 0..31
      h2 v = {(__fp16)0.f, (__fp16)0.f};
      if (valid) {
        const float x = src[((size_t)(2 * cp) << 15) + sd];
        const float y = src[((size_t)(2 * cp + 1) << 15) + sd];
        v = __builtin_amdgcn_cvt_pkrtz(x, y);
      }
      *(h2*)&dst[(4 + sd) * JSTR + 2 * cp] = v;  // [j=4+d][c] layout, rows 4..35
    }
  };

  // ---- prologue: in1 B-operand fragments for all 4 positions (static bfr indices)
  h8 bfr[4][2];
#pragma unroll
  for (int pos = 0; pos < 4; ++pos) {
    __syncthreads();
    stage(in1b + (h << 10) + ((w0 + pos) << 5), true, colbuf[0]);
    __syncthreads();
#pragma unroll
    for (int ch = 0; ch < 2; ++ch)
      bfr[pos][ch] =
          *(const h8*)&colbuf[0][(4 + db + l15) * JSTR + ch * 32 + (lhi << 3)];
  }
  __syncthreads();
  // stage first in2 column (ciLo) into colbuf[ciLo&1]
  {
    const int hcn = ciLo / 12;
    const int wcn = ciLo - hcn * 12;
    const int hp = h - 4 + hcn, wp = w0 - 4 + wcn;
    const bool valid = ((unsigned)hp < 32u) && ((unsigned)wp < 32u);
    stage(in2b + (hp << 10) + (wp << 5), valid, colbuf[ciLo & 1]);
  }
  __syncthreads();

  // band-write constants: m=(lhi*4+r), dz = jb+m-db-l15 = mr+r; off = dz*32+db+l15
  const int mr = jb - db + (lhi << 2) - l15;
  const int dzb = db + l15;

  // ---- main loop over this block's 27 columns, ONE barrier per column
  for (int ci = ciLo; ci < ciHi; ++ci) {
    // (1) issue next-column loads into registers (consumed at step 5)
    float lx[4], ly[4];
    bool nvalid = false;
    if (ci + 1 < ciHi) {
      const int cn = ci + 1;
      const int hcn = cn / 12;
      const int wcn = cn - hcn * 12;
      const int hp = h - 4 + hcn;
      const int wp = w0 - 4 + wcn;
      nvalid = ((unsigned)hp < 32u) && ((unsigned)wp < 32u);
      if (nvalid) {
        const float* src = in2b + (hp << 10) + (wp << 5);
#pragma unroll
        for (int it = 0; it < 4; ++it) {
          const int cp = scq + (it << 3);
          lx[it] = src[((size_t)(2 * cp) << 15) + sd];
          ly[it] = src[((size_t)(2 * cp + 1) << 15) + sd];
        }
      }
    }

    // (2,3) compute column ci for all 4 positions, band-write into obuf[ci&1]
    const int hc = ci / 12;
    const int wc = ci - hc * 12;

    const __fp16* cb = colbuf[ci & 1];
    float* ob = obuf[ci & 1];
    const h8 a0 = *(const h8*)&cb[(jb + l15) * JSTR + (lhi << 3)];
    const h8 a1 = *(const h8*)&cb[(jb + l15) * JSTR + 32 + (lhi << 3)];
#pragma unroll
    for (int pos = 0; pos < 4; ++pos) {
      if ((unsigned)(wc - pos) <= 8u) {  // dx = wc - pos in [0,9)
        f4 acc = {0.f, 0.f, 0.f, 0.f};
        acc = __builtin_amdgcn_mfma_f32_16x16x32_f16(a0, bfr[pos][0], acc, 0, 0, 0);
        acc = __builtin_amdgcn_mfma_f32_16x16x32_f16(a1, bfr[pos][1], acc, 0, 0, 0);
#pragma unroll
        for (int r = 0; r < 4; ++r) {
          const int dz = mr + r;
          if ((unsigned)dz < 9u) ob[pos * 288 + dz * 32 + dzb] = acc[r];
        }
      }
    }

    // (4) readback column ci-1 from obuf[(ci-1)&1]: 288 slots over 256 threads
    if (ci > ciLo) {
      const int cprev = ci - 1;
      const int hcp = cprev / 12;
      const int wcp = cprev - hcp * 12;
      const float* op = obuf[cprev & 1];
      for (int s = tid; s < 288; s += 256) {
        const int pos = s / 72;
        const int rr = s - pos * 72;
        const int dz = rr >> 3;
        const int q = rr & 7;
        if ((unsigned)(wcp - pos) <= 8u) {
          const f4 v = *(const f4*)&op[pos * 288 + dz * 32 + (q << 2)];
          const size_t chn = (size_t)(b * 729 + (hcp * 9 + (wcp - pos)) * 9 + dz);
          f4* dstp = (f4*)(out + (chn << 15) + (h << 10) + ((w0 + pos) << 5) + (q << 2));
          __builtin_nontemporal_store(v, dstp);
        }
      }
    }

    // (5) write staged column ci+1 into colbuf[(ci+1)&1] (compiler-inserted
    // vmcnt wait on lx/ly lands here; load latency hidden under steps 2-4)
    if (ci + 1 < ciHi) {
#pragma unroll
      for (int it = 0; it < 4; ++it) {
        const int cp = scq + (it << 3);
        h2 v = {(__fp16)0.f, (__fp16)0.f};
        if (nvalid) v = __builtin_amdgcn_cvt_pkrtz(lx[it], ly[it]);
        *(h2*)&colbuf[(ci + 1) & 1][(4 + sd) * JSTR + 2 * cp] = v;
      }
    }

    // (6) T4 counted-drain barrier: order LDS only; leave NT stores and any
    // in-flight global loads pipelining across rounds. sched_barrier(0) pins
    // the preceding ds ops to this side of the asm (guide rule #18).
    __builtin_amdgcn_sched_barrier(0);
    asm volatile("s_waitcnt lgkmcnt(0)" ::: "memory");
    __builtin_amdgcn_s_barrier();
    __builtin_amdgcn_sched_barrier(0);
  }

  // ---- epilogue: readback this range's last column
  {
    const int cl = ciHi - 1;
    const int hcp = cl / 12;
    const int wcp = cl - hcp * 12;
    const float* op = obuf[cl & 1];
    for (int s = tid; s < 288; s += 256) {
      const int pos = s / 72;
      const int rr = s - pos * 72;
      const int dz = rr >> 3;
      const int q = rr & 7;
      if ((unsigned)(wcp - pos) <= 8u) {
        const f4 v = *(const f4*)&op[pos * 288 + dz * 32 + (q << 2)];
        const size_t chn = (size_t)(b * 729 + (hcp * 9 + (wcp - pos)) * 9 + dz);
        f4* dstp = (f4*)(out + (chn << 15) + (h << 10) + ((w0 + pos) << 5) + (q << 2));
        __builtin_nontemporal_store(v, dstp);
      }
    }
  }
}

extern "C" void kernel_launch(void* const* d_in, const int* in_sizes, int n_in,
                              void* d_out, int out_size, void* d_ws, size_t ws_size,
                              hipStream_t stream) {
  const float* in1 = (const float*)d_in[0];
  const float* in2 = (const float*)d_in[1];
  float* out = (float*)d_out;
  corr3d_mfma<<<dim3(2048), dim3(256), 0, stream>>>(in1, in2, out);
}